// Round 10
// baseline (664.283 us; speedup 1.0000x reference)
//
#include <hip/hip_runtime.h>

#define E_TOTAL 1000000
#define EMB     128
#define NRBF    16
#define NATOMS  50000
#define APB     16                         // atoms per block (50000 = 3125*16)
#define NBLK    ((NATOMS + 255) / 256)     // scan blocks

typedef _Float16 f16x8 __attribute__((ext_vector_type(8)));
typedef _Float16 f16x4 __attribute__((ext_vector_type(4)));
typedef float    f32x4 __attribute__((ext_vector_type(4)));

__device__ __forceinline__ float silu_f(float v) {
    return v * (1.0f / (1.0f + __expf(-v)));
}

// ---------------------------------------------------------------------------
// CSR build: counting sort of edge ids by destination atom.
// ---------------------------------------------------------------------------
__global__ __launch_bounds__(256)
void hist_kernel(const int* __restrict__ idnb, int* __restrict__ counts) {
    const int e = blockIdx.x * 256 + threadIdx.x;
    if (e < E_TOTAL) atomicAdd(&counts[idnb[e]], 1);
}

__global__ __launch_bounds__(256)
void scan1_kernel(const int* __restrict__ counts, int* __restrict__ row_ptr,
                  int* __restrict__ bsums) {
    __shared__ int sd[256];
    const int tid = threadIdx.x;
    const int idx = blockIdx.x * 256 + tid;
    const int v = (idx < NATOMS) ? counts[idx] : 0;
    sd[tid] = v;
    __syncthreads();
#pragma unroll
    for (int off = 1; off < 256; off <<= 1) {
        const int t = (tid >= off) ? sd[tid - off] : 0;
        __syncthreads();
        sd[tid] += t;
        __syncthreads();
    }
    if (idx < NATOMS) row_ptr[idx] = sd[tid] - v;
    if (tid == 255) bsums[blockIdx.x] = sd[255];
}

__global__ __launch_bounds__(256)
void scan2_kernel(int* __restrict__ bsums) {
    __shared__ int sd[256];
    const int tid = threadIdx.x;
    const int v = (tid < NBLK) ? bsums[tid] : 0;
    sd[tid] = v;
    __syncthreads();
#pragma unroll
    for (int off = 1; off < 256; off <<= 1) {
        const int t = (tid >= off) ? sd[tid - off] : 0;
        __syncthreads();
        sd[tid] += t;
        __syncthreads();
    }
    if (tid < NBLK) bsums[tid] = sd[tid] - v;
}

__global__ __launch_bounds__(256)
void scan3_kernel(const int* __restrict__ bsums, int* __restrict__ row_ptr,
                  int* __restrict__ cursor) {
    const int idx = blockIdx.x * 256 + threadIdx.x;
    if (idx < NATOMS) {
        const int r = row_ptr[idx] + bsums[blockIdx.x];
        row_ptr[idx] = r;
        cursor[idx]  = r;
    }
    if (idx == 0) row_ptr[NATOMS] = E_TOTAL;
}

__global__ __launch_bounds__(256)
void scatter_kernel(const int* __restrict__ idnb, int* __restrict__ cursor,
                    int* __restrict__ eidx, int* __restrict__ aidxs) {
    const int e = blockIdx.x * 256 + threadIdx.x;
    if (e < E_TOTAL) {
        const int a = idnb[e];
        const int p = atomicAdd(&cursor[a], 1);
        eidx[p]  = e;
        aidxs[p] = a;
    }
}

// ---------------------------------------------------------------------------
// MFMA edge kernel — template ablation (EPI=0: epilogue removed, MFMA kept
// live via asm sinks, writes NOTHING; EPI=1: full kernel, r8-identical).
// Both instantiations launched back-to-back: per-dispatch rocprof rows give a
// within-run A/B bisecting {staging+MFMA} vs {gate+merge+LDS-atomic+store}.
// ---------------------------------------------------------------------------
template <int EPI>
__global__ __launch_bounds__(256, 2)
void edge_kernel(const float* __restrict__ x,
                 const float* __restrict__ rbf,
                 const int*   __restrict__ eidx,
                 const int*   __restrict__ aidxs,
                 const int*   __restrict__ row_ptr,
                 const float* __restrict__ Wx,
                 const float* __restrict__ bx,
                 const float* __restrict__ Wr,
                 const float* __restrict__ br,
                 const float* __restrict__ c_a,
                 const float* __restrict__ c_b,
                 const float* __restrict__ c_x,
                 float* __restrict__ acc)
{
    __shared__ _Float16 sX[2][64 * 128];  // 32 KB, XOR-swizzled 8-f16 groups
    __shared__ _Float16 sR[2][64 * 40];   // 10 KB, stride-40 pad, k>=16 zero
    __shared__ float    sAcc[APB][132];   // 8.4 KB
    __shared__ int      sAid[2][64];

    const int tid  = threadIdx.x;
    const int w    = tid >> 6;
    const int lane = tid & 63;
    const int lq   = lane >> 4;
    const int lm   = lane & 15;

    const int aBase = blockIdx.x * APB;
    const int eBeg  = row_ptr[aBase];
    const int eEnd  = row_ptr[aBase + APB];
    const int nEdge = eEnd - eBeg;
    const int ntile = (nEdge + 63) >> 6;

    const float ca = c_a[0];
    const float sc = c_b[0] * c_x[0];
    const int col0 = w * 32 + lm;
    const int col1 = col0 + 16;
    const float bx0 = bx[col0], bx1 = bx[col1];
    const float br0 = br[col0], br1 = br[col1];

    // ---- hoist split-W fragments from global, once per block ----
    f16x8 wxh[4][2], wxl[4][2], wrh[2], wrl[2];
#pragma unroll
    for (int ks = 0; ks < 4; ++ks)
#pragma unroll
        for (int nt = 0; nt < 2; ++nt) {
            const int n = w * 32 + nt * 16 + lm;
            f16x8 h8, l8;
#pragma unroll
            for (int j = 0; j < 8; ++j) {
                const int k = ks * 32 + lq * 8 + j;
                const float v = Wx[k * EMB + n];
                const _Float16 hv = (_Float16)v;
                h8[j] = hv;
                l8[j] = (_Float16)(v - (float)hv);
            }
            wxh[ks][nt] = h8;
            wxl[ks][nt] = l8;
        }
#pragma unroll
    for (int nt = 0; nt < 2; ++nt) {
        const int n = w * 32 + nt * 16 + lm;
        f16x8 h8, l8;
#pragma unroll
        for (int j = 0; j < 8; ++j) {
            const int k = lq * 8 + j;
            const float v = (k < NRBF) ? Wr[k * EMB + n] : 0.f;
            const _Float16 hv = (_Float16)v;
            h8[j] = hv;
            l8[j] = (_Float16)(v - (float)hv);
        }
        wrh[nt] = h8;
        wrl[nt] = l8;
    }

    // init LDS: zero accumulator (EPI only); zero sR k in [16,40) both buffers
    if constexpr (EPI) {
        for (int f = tid; f < APB * 132; f += 256) ((float*)sAcc)[f] = 0.f;
    }
    for (int f = tid; f < 64 * 24; f += 256) {
        sR[0][(f / 24) * 40 + 16 + (f % 24)] = (_Float16)0.f;
        sR[1][(f / 24) * 40 + 16 + (f % 24)] = (_Float16)0.f;
    }

    float4 px[8];
    float4 pr;
    int    prel = -1;

    auto prefetch = [&](int t) {
        const int nb = eBeg + t * 64;
#pragma unroll
        for (int i = 0; i < 8; ++i) {
            const int e = (tid >> 5) + i * 8;
            const int eid = eidx[min(nb + e, eEnd - 1)];
            px[i] = *(const float4*)(x + (size_t)eid * EMB + (tid & 31) * 4);
        }
        {
            const int er = tid >> 2;
            const int eid = eidx[min(nb + er, eEnd - 1)];
            pr = *(const float4*)(rbf + (size_t)eid * NRBF + (tid & 3) * 4);
        }
        if (tid < 64) prel = (nb + tid < eEnd) ? (aidxs[nb + tid] - aBase) : -1;
    };

    auto write_lds = [&](int buf) {
#pragma unroll
        for (int i = 0; i < 8; ++i) {
            const int e = (tid >> 5) + i * 8;
            const int kb = (tid & 31) * 4;
            const int idx = (e * 128 + kb) ^ ((e & 7) << 3);
            f16x4 h4 = {(_Float16)px[i].x, (_Float16)px[i].y,
                        (_Float16)px[i].z, (_Float16)px[i].w};
            *(f16x4*)&sX[buf][idx] = h4;
        }
        {
            const int er = tid >> 2;
            const int kb = (tid & 3) * 4;
            f16x4 r4 = {(_Float16)(pr.x * ca), (_Float16)(pr.y * ca),
                        (_Float16)(pr.z * ca), (_Float16)(pr.w * ca)};
            *(f16x4*)&sR[buf][er * 40 + kb] = r4;
        }
        if (tid < 64) sAid[buf][tid] = prel;
    };

    if (ntile > 0) {
        prefetch(0);
        write_lds(0);
        if (ntile > 1) prefetch(1);
    }
    __syncthreads();

    for (int t = 0; t < ntile; ++t) {
        const int cur = t & 1;
        const _Float16* sXc = sX[cur];
        const _Float16* sRc = sR[cur];
        const int*      sAc = sAid[cur];

#pragma unroll
        for (int mt = 0; mt < 4; ++mt) {
            f32x4 hac[2], gac[2];
#pragma unroll
            for (int nt = 0; nt < 2; ++nt) { hac[nt] = 0.f; gac[nt] = 0.f; }

            const int m = mt * 16 + lm;
            const f16x8 rh = *(const f16x8*)&sRc[m * 40 + lq * 8];
#pragma unroll
            for (int nt = 0; nt < 2; ++nt) {
                gac[nt] = __builtin_amdgcn_mfma_f32_16x16x32_f16(rh, wrh[nt], gac[nt], 0, 0, 0);
                gac[nt] = __builtin_amdgcn_mfma_f32_16x16x32_f16(rh, wrl[nt], gac[nt], 0, 0, 0);
            }
#pragma unroll
            for (int ks = 0; ks < 4; ++ks) {
                const int xi = (m * 128 + ks * 32 + lq * 8) ^ ((m & 7) << 3);
                const f16x8 xh = *(const f16x8*)&sXc[xi];
#pragma unroll
                for (int nt = 0; nt < 2; ++nt) {
                    hac[nt] = __builtin_amdgcn_mfma_f32_16x16x32_f16(xh, wxh[ks][nt], hac[nt], 0, 0, 0);
                    hac[nt] = __builtin_amdgcn_mfma_f32_16x16x32_f16(xh, wxl[ks][nt], hac[nt], 0, 0, 0);
                }
            }

            if constexpr (EPI) {
                // ---- epilogue: fused gate, run-merge, ds_add (r8-identical) ----
                const int embase = mt * 16 + lq * 4;   // C row = lq*4 + reg (m89)
                int rels[4];
#pragma unroll
                for (int r = 0; r < 4; ++r) rels[r] = sAc[embase + r];
                float v0[4], v1[4];
#pragma unroll
                for (int r = 0; r < 4; ++r) {
                    const float g0 = gac[0][r] + br0, h0 = hac[0][r] + bx0;
                    const float g1 = gac[1][r] + br1, h1 = hac[1][r] + bx1;
                    const float d0 = (1.f + __expf(-g0)) * (1.f + __expf(-h0));
                    const float d1 = (1.f + __expf(-g1)) * (1.f + __expf(-h1));
                    v0[r] = sc * g0 * h0 * __builtin_amdgcn_rcpf(d0);
                    v1[r] = sc * g1 * h1 * __builtin_amdgcn_rcpf(d1);
                }
                int cur2 = rels[0];
                float a0v = v0[0], a1v = v1[0];
#pragma unroll
                for (int r = 1; r < 4; ++r) {
                    if (rels[r] == cur2) {
                        a0v += v0[r]; a1v += v1[r];
                    } else {
                        if (cur2 >= 0) {
                            atomicAdd(&sAcc[cur2][col0], a0v);
                            atomicAdd(&sAcc[cur2][col1], a1v);
                        }
                        cur2 = rels[r]; a0v = v0[r]; a1v = v1[r];
                    }
                }
                if (cur2 >= 0) {
                    atomicAdd(&sAcc[cur2][col0], a0v);
                    atomicAdd(&sAcc[cur2][col1], a1v);
                }
            } else {
                // keep MFMA results live without epilogue cost (rule #17)
#pragma unroll
                for (int nt = 0; nt < 2; ++nt)
#pragma unroll
                    for (int r = 0; r < 4; ++r)
                        asm volatile("" :: "v"(hac[nt][r]), "v"(gac[nt][r]));
            }
        }

        if (t + 1 < ntile) {
            write_lds((t + 1) & 1);
            if (t + 2 < ntile) prefetch(t + 2);
        }
        __syncthreads();
    }

    if constexpr (EPI) {
        const int r = tid >> 4;
        const int c = (tid & 15) * 8;
        float* dst = acc + (size_t)(aBase + r) * EMB + c;
        *(float4*)(dst)     = *(const float4*)&sAcc[r][c];
        *(float4*)(dst + 4) = *(const float4*)&sAcc[r][c + 4];
    }
}

// ---------------------------------------------------------------------------
// MFMA atom-MLP layer: Y = silu(X @ W + b). 2 subtiles of 64 rows per block.
// ---------------------------------------------------------------------------
__global__ __launch_bounds__(256, 2)
void layer_kernel(const float* __restrict__ X,
                  const float* __restrict__ W,
                  const float* __restrict__ b,
                  float* __restrict__ Y, int M)
{
    __shared__ _Float16 sX[64 * 128];

    const int tid  = threadIdx.x;
    const int w    = tid >> 6;
    const int lane = tid & 63;
    const int lq   = lane >> 4;
    const int lm   = lane & 15;

    const int col0 = w * 32 + lm;
    const int col1 = col0 + 16;
    const float b0 = b[col0], b1 = b[col1];

    f16x8 wh[4][2], wl[4][2];
#pragma unroll
    for (int ks = 0; ks < 4; ++ks)
#pragma unroll
        for (int nt = 0; nt < 2; ++nt) {
            const int n = w * 32 + nt * 16 + lm;
            f16x8 h8, l8;
#pragma unroll
            for (int j = 0; j < 8; ++j) {
                const int k = ks * 32 + lq * 8 + j;
                const float v = W[k * EMB + n];
                const _Float16 hv = (_Float16)v;
                h8[j] = hv;
                l8[j] = (_Float16)(v - (float)hv);
            }
            wh[ks][nt] = h8;
            wl[ks][nt] = l8;
        }

#pragma unroll
    for (int sub = 0; sub < 2; ++sub) {
        const int base = blockIdx.x * 128 + sub * 64;
        __syncthreads();
#pragma unroll
        for (int i = 0; i < 8; ++i) {
            const int e = (tid >> 5) + i * 8;
            const int row = min(base + e, M - 1);
            const float4 v = *(const float4*)(X + (size_t)row * EMB + (tid & 31) * 4);
            const int kb = (tid & 31) * 4;
            const int idx = (e * 128 + kb) ^ ((e & 7) << 3);
            f16x4 h4 = {(_Float16)v.x, (_Float16)v.y, (_Float16)v.z, (_Float16)v.w};
            *(f16x4*)&sX[idx] = h4;
        }
        __syncthreads();

#pragma unroll
        for (int mth = 0; mth < 2; ++mth) {
            f32x4 hac[2][2];
#pragma unroll
            for (int mi = 0; mi < 2; ++mi)
#pragma unroll
                for (int nt = 0; nt < 2; ++nt) hac[mi][nt] = 0.f;

#pragma unroll
            for (int mi = 0; mi < 2; ++mi) {
                const int m = (mth * 2 + mi) * 16 + lm;
#pragma unroll
                for (int ks = 0; ks < 4; ++ks) {
                    const int xi = (m * 128 + ks * 32 + lq * 8) ^ ((m & 7) << 3);
                    const f16x8 xh = *(const f16x8*)&sX[xi];
#pragma unroll
                    for (int nt = 0; nt < 2; ++nt) {
                        hac[mi][nt] = __builtin_amdgcn_mfma_f32_16x16x32_f16(xh, wh[ks][nt], hac[mi][nt], 0, 0, 0);
                        hac[mi][nt] = __builtin_amdgcn_mfma_f32_16x16x32_f16(xh, wl[ks][nt], hac[mi][nt], 0, 0, 0);
                    }
                }
            }
#pragma unroll
            for (int mi = 0; mi < 2; ++mi) {
                const int rb = base + (mth * 2 + mi) * 16 + lq * 4;
#pragma unroll
                for (int r = 0; r < 4; ++r) {
                    const int row = rb + r;
                    if (row < M) {
                        Y[(size_t)row * EMB + col0] = silu_f(hac[mi][0][r] + b0);
                        Y[(size_t)row * EMB + col1] = silu_f(hac[mi][1][r] + b1);
                    }
                }
            }
        }
    }
}

// ---------------------------------------------------------------------------
// Fused layer-3 + final projection: out[row] = (silu(X@W3+b3) @ Wf) * cf.
// Per-row dot reduced via 16-lane shfl_xor + per-block LDS row sums.
// ---------------------------------------------------------------------------
__global__ __launch_bounds__(256, 2)
void layer3_final_kernel(const float* __restrict__ X,
                         const float* __restrict__ W,
                         const float* __restrict__ b,
                         const float* __restrict__ Wf,
                         const float* __restrict__ cf,
                         float* __restrict__ out, int M)
{
    __shared__ _Float16 sX[64 * 128];
    __shared__ float    sOut[128];

    const int tid  = threadIdx.x;
    const int w    = tid >> 6;
    const int lane = tid & 63;
    const int lq   = lane >> 4;
    const int lm   = lane & 15;

    const int col0 = w * 32 + lm;
    const int col1 = col0 + 16;
    const float b0 = b[col0], b1 = b[col1];
    const float wf0 = Wf[col0], wf1 = Wf[col1];
    const float cfv = cf[0];

    if (tid < 128) sOut[tid] = 0.f;

    f16x8 wh[4][2], wl[4][2];
#pragma unroll
    for (int ks = 0; ks < 4; ++ks)
#pragma unroll
        for (int nt = 0; nt < 2; ++nt) {
            const int n = w * 32 + nt * 16 + lm;
            f16x8 h8, l8;
#pragma unroll
            for (int j = 0; j < 8; ++j) {
                const int k = ks * 32 + lq * 8 + j;
                const float v = W[k * EMB + n];
                const _Float16 hv = (_Float16)v;
                h8[j] = hv;
                l8[j] = (_Float16)(v - (float)hv);
            }
            wh[ks][nt] = h8;
            wl[ks][nt] = l8;
        }

#pragma unroll
    for (int sub = 0; sub < 2; ++sub) {
        const int base = blockIdx.x * 128 + sub * 64;
        __syncthreads();
#pragma unroll
        for (int i = 0; i < 8; ++i) {
            const int e = (tid >> 5) + i * 8;
            const int row = min(base + e, M - 1);
            const float4 v = *(const float4*)(X + (size_t)row * EMB + (tid & 31) * 4);
            const int kb = (tid & 31) * 4;
            const int idx = (e * 128 + kb) ^ ((e & 7) << 3);
            f16x4 h4 = {(_Float16)v.x, (_Float16)v.y, (_Float16)v.z, (_Float16)v.w};
            *(f16x4*)&sX[idx] = h4;
        }
        __syncthreads();

#pragma unroll
        for (int mth = 0; mth < 2; ++mth) {
            f32x4 hac[2][2];
#pragma unroll
            for (int mi = 0; mi < 2; ++mi)
#pragma unroll
                for (int nt = 0; nt < 2; ++nt) hac[mi][nt] = 0.f;

#pragma unroll
            for (int mi = 0; mi < 2; ++mi) {
                const int m = (mth * 2 + mi) * 16 + lm;
#pragma unroll
                for (int ks = 0; ks < 4; ++ks) {
                    const int xi = (m * 128 + ks * 32 + lq * 8) ^ ((m & 7) << 3);
                    const f16x8 xh = *(const f16x8*)&sX[xi];
#pragma unroll
                    for (int nt = 0; nt < 2; ++nt) {
                        hac[mi][nt] = __builtin_amdgcn_mfma_f32_16x16x32_f16(xh, wh[ks][nt], hac[mi][nt], 0, 0, 0);
                        hac[mi][nt] = __builtin_amdgcn_mfma_f32_16x16x32_f16(xh, wl[ks][nt], hac[mi][nt], 0, 0, 0);
                    }
                }
            }
#pragma unroll
            for (int mi = 0; mi < 2; ++mi) {
                const int lrow = sub * 64 + (mth * 2 + mi) * 16 + lq * 4;
#pragma unroll
                for (int r = 0; r < 4; ++r) {
                    const float o0 = silu_f(hac[mi][0][r] + b0);
                    const float o1 = silu_f(hac[mi][1][r] + b1);
                    float p = o0 * wf0 + o1 * wf1;
#pragma unroll
                    for (int off = 1; off < 16; off <<= 1)
                        p += __shfl_xor(p, off);
                    if (lm == 0 && base + (mth * 2 + mi) * 16 + lq * 4 + r < M)
                        atomicAdd(&sOut[lrow + r], p);
                }
            }
        }
    }

    __syncthreads();
    if (tid < 128) {
        const int row = blockIdx.x * 128 + tid;
        if (row < M) out[row] = sOut[tid] * cfv;
    }
}

extern "C" void kernel_launch(void* const* d_in, const int* in_sizes, int n_in,
                              void* d_out, int out_size, void* d_ws, size_t ws_size,
                              hipStream_t stream) {
    const float* x    = (const float*)d_in[0];
    const float* rbf  = (const float*)d_in[1];
    const int*   idnb = (const int*)  d_in[2];
    // d_in[3] = n_atoms (fixed 50000)
    const float* Wx   = (const float*)d_in[4];
    const float* bx   = (const float*)d_in[5];
    const float* Wr   = (const float*)d_in[6];
    const float* brf  = (const float*)d_in[7];
    const float* W1   = (const float*)d_in[8];
    const float* b1   = (const float*)d_in[9];
    const float* W2   = (const float*)d_in[10];
    const float* b2   = (const float*)d_in[11];
    const float* W3   = (const float*)d_in[12];
    const float* b3   = (const float*)d_in[13];
    const float* Wf   = (const float*)d_in[14];
    const float* c_a  = (const float*)d_in[15];
    const float* c_b  = (const float*)d_in[16];
    const float* c_x  = (const float*)d_in[17];
    const float* c_f  = (const float*)d_in[18];

    float* out = (float*)d_out;
    float* acc = (float*)d_ws;                        // [NATOMS][128] f32
    float* buf = acc + (size_t)NATOMS * EMB;          // [NATOMS][128] f32
    // CSR scratch inside buf (dead before layer 1 writes buf)
    int* eidx    = (int*)buf;                         // 1M
    int* aidxs   = eidx + E_TOTAL;                    // 1M
    int* counts  = aidxs + E_TOTAL;                   // NATOMS
    int* row_ptr = counts + NATOMS;                   // NATOMS+1
    int* cursor  = row_ptr + NATOMS + 1;              // NATOMS
    int* bsums   = cursor + NATOMS;                   // NBLK

    hipMemsetAsync(counts, 0, NATOMS * sizeof(int), stream);

    hist_kernel<<<(E_TOTAL + 255) / 256, 256, 0, stream>>>(idnb, counts);
    scan1_kernel<<<NBLK, 256, 0, stream>>>(counts, row_ptr, bsums);
    scan2_kernel<<<1, 256, 0, stream>>>(bsums);
    scan3_kernel<<<NBLK, 256, 0, stream>>>(bsums, row_ptr, cursor);
    scatter_kernel<<<(E_TOTAL + 255) / 256, 256, 0, stream>>>(idnb, cursor, eidx, aidxs);

    // A/B ablation: dispatch 1 = no-epilogue probe (writes nothing, isolates
    // staging+MFMA); dispatch 2 = full kernel (produces the result).
    edge_kernel<0><<<NATOMS / APB, 256, 0, stream>>>(x, rbf, eidx, aidxs, row_ptr,
                                                     Wx, bx, Wr, brf,
                                                     c_a, c_b, c_x, acc);
    edge_kernel<1><<<NATOMS / APB, 256, 0, stream>>>(x, rbf, eidx, aidxs, row_ptr,
                                                     Wx, bx, Wr, brf,
                                                     c_a, c_b, c_x, acc);

    const int ltiles = (NATOMS + 127) / 128;          // 391
    layer_kernel<<<ltiles, 256, 0, stream>>>(acc, W1, b1, buf, NATOMS);
    layer_kernel<<<ltiles, 256, 0, stream>>>(buf, W2, b2, acc, NATOMS);
    layer3_final_kernel<<<ltiles, 256, 0, stream>>>(acc, W3, b3, Wf, c_f, out, NATOMS);
}

// Round 11
// 421.357 us; speedup vs baseline: 1.5765x; 1.5765x over previous
//
#include <hip/hip_runtime.h>

#define E_TOTAL 1000000
#define EMB     128
#define NRBF    16
#define NATOMS  50000
#define APB     16                         // atoms per block (50000 = 3125*16)
#define NBLK    ((NATOMS + 255) / 256)     // scan blocks

typedef _Float16 f16x8 __attribute__((ext_vector_type(8)));
typedef _Float16 f16x4 __attribute__((ext_vector_type(4)));
typedef float    f32x4 __attribute__((ext_vector_type(4)));

__device__ __forceinline__ float silu_f(float v) {
    return v * (1.0f / (1.0f + __expf(-v)));
}

// LDS row e holds sorted edge sigma(e): lane-quarter lq's C-rows across the
// 4 mt steps then cover sorted positions lq*16..lq*16+15 consecutively.
__device__ __forceinline__ int sigma64(int e) {
    return (((e & 15) >> 2) << 4) + ((e >> 4) << 2) + (e & 3);
}

// ---------------------------------------------------------------------------
// CSR build: counting sort of edge ids by destination atom.
// ---------------------------------------------------------------------------
__global__ __launch_bounds__(256)
void hist_kernel(const int* __restrict__ idnb, int* __restrict__ counts) {
    const int e = blockIdx.x * 256 + threadIdx.x;
    if (e < E_TOTAL) atomicAdd(&counts[idnb[e]], 1);
}

__global__ __launch_bounds__(256)
void scan1_kernel(const int* __restrict__ counts, int* __restrict__ row_ptr,
                  int* __restrict__ bsums) {
    __shared__ int sd[256];
    const int tid = threadIdx.x;
    const int idx = blockIdx.x * 256 + tid;
    const int v = (idx < NATOMS) ? counts[idx] : 0;
    sd[tid] = v;
    __syncthreads();
#pragma unroll
    for (int off = 1; off < 256; off <<= 1) {
        const int t = (tid >= off) ? sd[tid - off] : 0;
        __syncthreads();
        sd[tid] += t;
        __syncthreads();
    }
    if (idx < NATOMS) row_ptr[idx] = sd[tid] - v;
    if (tid == 255) bsums[blockIdx.x] = sd[255];
}

__global__ __launch_bounds__(256)
void scan2_kernel(int* __restrict__ bsums) {
    __shared__ int sd[256];
    const int tid = threadIdx.x;
    const int v = (tid < NBLK) ? bsums[tid] : 0;
    sd[tid] = v;
    __syncthreads();
#pragma unroll
    for (int off = 1; off < 256; off <<= 1) {
        const int t = (tid >= off) ? sd[tid - off] : 0;
        __syncthreads();
        sd[tid] += t;
        __syncthreads();
    }
    if (tid < NBLK) bsums[tid] = sd[tid] - v;
}

__global__ __launch_bounds__(256)
void scan3_kernel(const int* __restrict__ bsums, int* __restrict__ row_ptr,
                  int* __restrict__ cursor) {
    const int idx = blockIdx.x * 256 + threadIdx.x;
    if (idx < NATOMS) {
        const int r = row_ptr[idx] + bsums[blockIdx.x];
        row_ptr[idx] = r;
        cursor[idx]  = r;
    }
    if (idx == 0) row_ptr[NATOMS] = E_TOTAL;
}

__global__ __launch_bounds__(256)
void scatter_kernel(const int* __restrict__ idnb, int* __restrict__ cursor,
                    int* __restrict__ eidx, int* __restrict__ aidxs) {
    const int e = blockIdx.x * 256 + threadIdx.x;
    if (e < E_TOTAL) {
        const int a = idnb[e];
        const int p = atomicAdd(&cursor[a], 1);
        eidx[p]  = e;
        aidxs[p] = a;
    }
}

// ---------------------------------------------------------------------------
// MFMA edge kernel. r8 data path (double-buffer, single barrier, fused gate)
// + sigma-permuted edge->C-row mapping + run-merge CARRIED across the 4 mt
// steps (per-lane runs of 16 sorted edges -> ~2.6x fewer LDS atomics, flush
// branch rarely taken).
// ---------------------------------------------------------------------------
__global__ __launch_bounds__(256, 2)
void edge_kernel(const float* __restrict__ x,
                 const float* __restrict__ rbf,
                 const int*   __restrict__ eidx,
                 const int*   __restrict__ aidxs,
                 const int*   __restrict__ row_ptr,
                 const float* __restrict__ Wx,
                 const float* __restrict__ bx,
                 const float* __restrict__ Wr,
                 const float* __restrict__ br,
                 const float* __restrict__ c_a,
                 const float* __restrict__ c_b,
                 const float* __restrict__ c_x,
                 float* __restrict__ acc)
{
    __shared__ _Float16 sX[2][64 * 128];  // 32 KB, XOR-swizzled 8-f16 groups
    __shared__ _Float16 sR[2][64 * 40];   // 10 KB, stride-40 pad, k>=16 zero
    __shared__ float    sAcc[APB][132];   // 8.4 KB
    __shared__ int      sAid[2][64];      // rel-atom of sorted pos p (not row)

    const int tid  = threadIdx.x;
    const int w    = tid >> 6;
    const int lane = tid & 63;
    const int lq   = lane >> 4;
    const int lm   = lane & 15;

    const int aBase = blockIdx.x * APB;
    const int eBeg  = row_ptr[aBase];
    const int eEnd  = row_ptr[aBase + APB];
    const int nEdge = eEnd - eBeg;
    const int ntile = (nEdge + 63) >> 6;

    const float ca = c_a[0];
    const float sc = c_b[0] * c_x[0];
    const int col0 = w * 32 + lm;
    const int col1 = col0 + 16;
    const float bx0 = bx[col0], bx1 = bx[col1];
    const float br0 = br[col0], br1 = br[col1];

    // ---- hoist split-W fragments from global, once per block ----
    f16x8 wxh[4][2], wxl[4][2], wrh[2], wrl[2];
#pragma unroll
    for (int ks = 0; ks < 4; ++ks)
#pragma unroll
        for (int nt = 0; nt < 2; ++nt) {
            const int n = w * 32 + nt * 16 + lm;
            f16x8 h8, l8;
#pragma unroll
            for (int j = 0; j < 8; ++j) {
                const int k = ks * 32 + lq * 8 + j;
                const float v = Wx[k * EMB + n];
                const _Float16 hv = (_Float16)v;
                h8[j] = hv;
                l8[j] = (_Float16)(v - (float)hv);
            }
            wxh[ks][nt] = h8;
            wxl[ks][nt] = l8;
        }
#pragma unroll
    for (int nt = 0; nt < 2; ++nt) {
        const int n = w * 32 + nt * 16 + lm;
        f16x8 h8, l8;
#pragma unroll
        for (int j = 0; j < 8; ++j) {
            const int k = lq * 8 + j;
            const float v = (k < NRBF) ? Wr[k * EMB + n] : 0.f;
            const _Float16 hv = (_Float16)v;
            h8[j] = hv;
            l8[j] = (_Float16)(v - (float)hv);
        }
        wrh[nt] = h8;
        wrl[nt] = l8;
    }

    // init LDS: zero accumulator; zero sR k in [16,40) for both buffers
    for (int f = tid; f < APB * 132; f += 256) ((float*)sAcc)[f] = 0.f;
    for (int f = tid; f < 64 * 24; f += 256) {
        sR[0][(f / 24) * 40 + 16 + (f % 24)] = (_Float16)0.f;
        sR[1][(f / 24) * 40 + 16 + (f % 24)] = (_Float16)0.f;
    }

    float4 px[8];
    float4 pr;
    int    prel = -1;

    auto prefetch = [&](int t) {
        const int nb = eBeg + t * 64;
#pragma unroll
        for (int i = 0; i < 8; ++i) {
            const int e = (tid >> 5) + i * 8;            // LDS row
            const int eid = eidx[min(nb + sigma64(e), eEnd - 1)];
            px[i] = *(const float4*)(x + (size_t)eid * EMB + (tid & 31) * 4);
        }
        {
            const int er = tid >> 2;                     // LDS row (rbf)
            const int eid = eidx[min(nb + sigma64(er), eEnd - 1)];
            pr = *(const float4*)(rbf + (size_t)eid * NRBF + (tid & 3) * 4);
        }
        // sAid stays in SORTED-position order
        if (tid < 64) prel = (nb + tid < eEnd) ? (aidxs[nb + tid] - aBase) : -1;
    };

    auto write_lds = [&](int buf) {
#pragma unroll
        for (int i = 0; i < 8; ++i) {
            const int e = (tid >> 5) + i * 8;
            const int kb = (tid & 31) * 4;
            const int idx = (e * 128 + kb) ^ ((e & 7) << 3);
            f16x4 h4 = {(_Float16)px[i].x, (_Float16)px[i].y,
                        (_Float16)px[i].z, (_Float16)px[i].w};
            *(f16x4*)&sX[buf][idx] = h4;
        }
        {
            const int er = tid >> 2;
            const int kb = (tid & 3) * 4;
            f16x4 r4 = {(_Float16)(pr.x * ca), (_Float16)(pr.y * ca),
                        (_Float16)(pr.z * ca), (_Float16)(pr.w * ca)};
            *(f16x4*)&sR[buf][er * 40 + kb] = r4;
        }
        if (tid < 64) sAid[buf][tid] = prel;
    };

    if (ntile > 0) {
        prefetch(0);
        write_lds(0);
        if (ntile > 1) prefetch(1);
    }
    __syncthreads();

    for (int t = 0; t < ntile; ++t) {
        const int cur = t & 1;
        const _Float16* sXc = sX[cur];
        const _Float16* sRc = sR[cur];
        const int*      sAc = sAid[cur];

        // run-merge state carried across all 4 mt steps (16-edge span/lane)
        int   curA = -2;
        float a0v = 0.f, a1v = 0.f;

#pragma unroll
        for (int mt = 0; mt < 4; ++mt) {
            f32x4 hac[2], gac[2];
#pragma unroll
            for (int nt = 0; nt < 2; ++nt) { hac[nt] = 0.f; gac[nt] = 0.f; }

            const int m = mt * 16 + lm;
            const f16x8 rh = *(const f16x8*)&sRc[m * 40 + lq * 8];
#pragma unroll
            for (int nt = 0; nt < 2; ++nt) {
                gac[nt] = __builtin_amdgcn_mfma_f32_16x16x32_f16(rh, wrh[nt], gac[nt], 0, 0, 0);
                gac[nt] = __builtin_amdgcn_mfma_f32_16x16x32_f16(rh, wrl[nt], gac[nt], 0, 0, 0);
            }
#pragma unroll
            for (int ks = 0; ks < 4; ++ks) {
                const int xi = (m * 128 + ks * 32 + lq * 8) ^ ((m & 7) << 3);
                const f16x8 xh = *(const f16x8*)&sXc[xi];
#pragma unroll
                for (int nt = 0; nt < 2; ++nt) {
                    hac[nt] = __builtin_amdgcn_mfma_f32_16x16x32_f16(xh, wxh[ks][nt], hac[nt], 0, 0, 0);
                    hac[nt] = __builtin_amdgcn_mfma_f32_16x16x32_f16(xh, wxl[ks][nt], hac[nt], 0, 0, 0);
                }
            }

            // ---- epilogue: fused gate, carried run-merge, rare ds_add ----
            // C-row (mt, lq*4+r) holds sorted position lq*16 + mt*4 + r.
            const int pbase = lq * 16 + mt * 4;
            float v0[4], v1[4];
#pragma unroll
            for (int r = 0; r < 4; ++r) {
                const float g0 = gac[0][r] + br0, h0 = hac[0][r] + bx0;
                const float g1 = gac[1][r] + br1, h1 = hac[1][r] + bx1;
                const float d0 = (1.f + __expf(-g0)) * (1.f + __expf(-h0));
                const float d1 = (1.f + __expf(-g1)) * (1.f + __expf(-h1));
                v0[r] = sc * g0 * h0 * __builtin_amdgcn_rcpf(d0);
                v1[r] = sc * g1 * h1 * __builtin_amdgcn_rcpf(d1);
            }
#pragma unroll
            for (int r = 0; r < 4; ++r) {
                const int rel = sAc[pbase + r];
                if (rel != curA) {                  // rarely taken (run ~20)
                    if (curA >= 0) {
                        atomicAdd(&sAcc[curA][col0], a0v);
                        atomicAdd(&sAcc[curA][col1], a1v);
                    }
                    curA = rel; a0v = 0.f; a1v = 0.f;
                }
                a0v += v0[r];
                a1v += v1[r];
            }
        }
        if (curA >= 0) {                            // final flush per tile
            atomicAdd(&sAcc[curA][col0], a0v);
            atomicAdd(&sAcc[curA][col1], a1v);
        }

        if (t + 1 < ntile) {
            write_lds((t + 1) & 1);
            if (t + 2 < ntile) prefetch(t + 2);
        }
        __syncthreads();
    }

    {
        const int r = tid >> 4;
        const int c = (tid & 15) * 8;
        float* dst = acc + (size_t)(aBase + r) * EMB + c;
        *(float4*)(dst)     = *(const float4*)&sAcc[r][c];
        *(float4*)(dst + 4) = *(const float4*)&sAcc[r][c + 4];
    }
}

// ---------------------------------------------------------------------------
// MFMA atom-MLP layer: Y = silu(X @ W + b). 2 subtiles of 64 rows per block.
// ---------------------------------------------------------------------------
__global__ __launch_bounds__(256, 2)
void layer_kernel(const float* __restrict__ X,
                  const float* __restrict__ W,
                  const float* __restrict__ b,
                  float* __restrict__ Y, int M)
{
    __shared__ _Float16 sX[64 * 128];

    const int tid  = threadIdx.x;
    const int w    = tid >> 6;
    const int lane = tid & 63;
    const int lq   = lane >> 4;
    const int lm   = lane & 15;

    const int col0 = w * 32 + lm;
    const int col1 = col0 + 16;
    const float b0 = b[col0], b1 = b[col1];

    f16x8 wh[4][2], wl[4][2];
#pragma unroll
    for (int ks = 0; ks < 4; ++ks)
#pragma unroll
        for (int nt = 0; nt < 2; ++nt) {
            const int n = w * 32 + nt * 16 + lm;
            f16x8 h8, l8;
#pragma unroll
            for (int j = 0; j < 8; ++j) {
                const int k = ks * 32 + lq * 8 + j;
                const float v = W[k * EMB + n];
                const _Float16 hv = (_Float16)v;
                h8[j] = hv;
                l8[j] = (_Float16)(v - (float)hv);
            }
            wh[ks][nt] = h8;
            wl[ks][nt] = l8;
        }

#pragma unroll
    for (int sub = 0; sub < 2; ++sub) {
        const int base = blockIdx.x * 128 + sub * 64;
        __syncthreads();
#pragma unroll
        for (int i = 0; i < 8; ++i) {
            const int e = (tid >> 5) + i * 8;
            const int row = min(base + e, M - 1);
            const float4 v = *(const float4*)(X + (size_t)row * EMB + (tid & 31) * 4);
            const int kb = (tid & 31) * 4;
            const int idx = (e * 128 + kb) ^ ((e & 7) << 3);
            f16x4 h4 = {(_Float16)v.x, (_Float16)v.y, (_Float16)v.z, (_Float16)v.w};
            *(f16x4*)&sX[idx] = h4;
        }
        __syncthreads();

#pragma unroll
        for (int mth = 0; mth < 2; ++mth) {
            f32x4 hac[2][2];
#pragma unroll
            for (int mi = 0; mi < 2; ++mi)
#pragma unroll
                for (int nt = 0; nt < 2; ++nt) hac[mi][nt] = 0.f;

#pragma unroll
            for (int mi = 0; mi < 2; ++mi) {
                const int m = (mth * 2 + mi) * 16 + lm;
#pragma unroll
                for (int ks = 0; ks < 4; ++ks) {
                    const int xi = (m * 128 + ks * 32 + lq * 8) ^ ((m & 7) << 3);
                    const f16x8 xh = *(const f16x8*)&sX[xi];
#pragma unroll
                    for (int nt = 0; nt < 2; ++nt) {
                        hac[mi][nt] = __builtin_amdgcn_mfma_f32_16x16x32_f16(xh, wh[ks][nt], hac[mi][nt], 0, 0, 0);
                        hac[mi][nt] = __builtin_amdgcn_mfma_f32_16x16x32_f16(xh, wl[ks][nt], hac[mi][nt], 0, 0, 0);
                    }
                }
            }
#pragma unroll
            for (int mi = 0; mi < 2; ++mi) {
                const int rb = base + (mth * 2 + mi) * 16 + lq * 4;
#pragma unroll
                for (int r = 0; r < 4; ++r) {
                    const int row = rb + r;
                    if (row < M) {
                        Y[(size_t)row * EMB + col0] = silu_f(hac[mi][0][r] + b0);
                        Y[(size_t)row * EMB + col1] = silu_f(hac[mi][1][r] + b1);
                    }
                }
            }
        }
    }
}

// ---------------------------------------------------------------------------
// Fused layer-3 + final projection: out[row] = (silu(X@W3+b3) @ Wf) * cf.
// ---------------------------------------------------------------------------
__global__ __launch_bounds__(256, 2)
void layer3_final_kernel(const float* __restrict__ X,
                         const float* __restrict__ W,
                         const float* __restrict__ b,
                         const float* __restrict__ Wf,
                         const float* __restrict__ cf,
                         float* __restrict__ out, int M)
{
    __shared__ _Float16 sX[64 * 128];
    __shared__ float    sOut[128];

    const int tid  = threadIdx.x;
    const int w    = tid >> 6;
    const int lane = tid & 63;
    const int lq   = lane >> 4;
    const int lm   = lane & 15;

    const int col0 = w * 32 + lm;
    const int col1 = col0 + 16;
    const float b0 = b[col0], b1 = b[col1];
    const float wf0 = Wf[col0], wf1 = Wf[col1];
    const float cfv = cf[0];

    if (tid < 128) sOut[tid] = 0.f;

    f16x8 wh[4][2], wl[4][2];
#pragma unroll
    for (int ks = 0; ks < 4; ++ks)
#pragma unroll
        for (int nt = 0; nt < 2; ++nt) {
            const int n = w * 32 + nt * 16 + lm;
            f16x8 h8, l8;
#pragma unroll
            for (int j = 0; j < 8; ++j) {
                const int k = ks * 32 + lq * 8 + j;
                const float v = W[k * EMB + n];
                const _Float16 hv = (_Float16)v;
                h8[j] = hv;
                l8[j] = (_Float16)(v - (float)hv);
            }
            wh[ks][nt] = h8;
            wl[ks][nt] = l8;
        }

#pragma unroll
    for (int sub = 0; sub < 2; ++sub) {
        const int base = blockIdx.x * 128 + sub * 64;
        __syncthreads();
#pragma unroll
        for (int i = 0; i < 8; ++i) {
            const int e = (tid >> 5) + i * 8;
            const int row = min(base + e, M - 1);
            const float4 v = *(const float4*)(X + (size_t)row * EMB + (tid & 31) * 4);
            const int kb = (tid & 31) * 4;
            const int idx = (e * 128 + kb) ^ ((e & 7) << 3);
            f16x4 h4 = {(_Float16)v.x, (_Float16)v.y, (_Float16)v.z, (_Float16)v.w};
            *(f16x4*)&sX[idx] = h4;
        }
        __syncthreads();

#pragma unroll
        for (int mth = 0; mth < 2; ++mth) {
            f32x4 hac[2][2];
#pragma unroll
            for (int mi = 0; mi < 2; ++mi)
#pragma unroll
                for (int nt = 0; nt < 2; ++nt) hac[mi][nt] = 0.f;

#pragma unroll
            for (int mi = 0; mi < 2; ++mi) {
                const int m = (mth * 2 + mi) * 16 + lm;
#pragma unroll
                for (int ks = 0; ks < 4; ++ks) {
                    const int xi = (m * 128 + ks * 32 + lq * 8) ^ ((m & 7) << 3);
                    const f16x8 xh = *(const f16x8*)&sX[xi];
#pragma unroll
                    for (int nt = 0; nt < 2; ++nt) {
                        hac[mi][nt] = __builtin_amdgcn_mfma_f32_16x16x32_f16(xh, wh[ks][nt], hac[mi][nt], 0, 0, 0);
                        hac[mi][nt] = __builtin_amdgcn_mfma_f32_16x16x32_f16(xh, wl[ks][nt], hac[mi][nt], 0, 0, 0);
                    }
                }
            }
#pragma unroll
            for (int mi = 0; mi < 2; ++mi) {
                const int lrow = sub * 64 + (mth * 2 + mi) * 16 + lq * 4;
#pragma unroll
                for (int r = 0; r < 4; ++r) {
                    const float o0 = silu_f(hac[mi][0][r] + b0);
                    const float o1 = silu_f(hac[mi][1][r] + b1);
                    float p = o0 * wf0 + o1 * wf1;
#pragma unroll
                    for (int off = 1; off < 16; off <<= 1)
                        p += __shfl_xor(p, off);
                    if (lm == 0 && base + (mth * 2 + mi) * 16 + lq * 4 + r < M)
                        atomicAdd(&sOut[lrow + r], p);
                }
            }
        }
    }

    __syncthreads();
    if (tid < 128) {
        const int row = blockIdx.x * 128 + tid;
        if (row < M) out[row] = sOut[tid] * cfv;
    }
}

extern "C" void kernel_launch(void* const* d_in, const int* in_sizes, int n_in,
                              void* d_out, int out_size, void* d_ws, size_t ws_size,
                              hipStream_t stream) {
    const float* x    = (const float*)d_in[0];
    const float* rbf  = (const float*)d_in[1];
    const int*   idnb = (const int*)  d_in[2];
    // d_in[3] = n_atoms (fixed 50000)
    const float* Wx   = (const float*)d_in[4];
    const float* bx   = (const float*)d_in[5];
    const float* Wr   = (const float*)d_in[6];
    const float* brf  = (const float*)d_in[7];
    const float* W1   = (const float*)d_in[8];
    const float* b1   = (const float*)d_in[9];
    const float* W2   = (const float*)d_in[10];
    const float* b2   = (const float*)d_in[11];
    const float* W3   = (const float*)d_in[12];
    const float* b3   = (const float*)d_in[13];
    const float* Wf   = (const float*)d_in[14];
    const float* c_a  = (const float*)d_in[15];
    const float* c_b  = (const float*)d_in[16];
    const float* c_x  = (const float*)d_in[17];
    const float* c_f  = (const float*)d_in[18];

    float* out = (float*)d_out;
    float* acc = (float*)d_ws;                        // [NATOMS][128] f32
    float* buf = acc + (size_t)NATOMS * EMB;          // [NATOMS][128] f32
    // CSR scratch inside buf (dead before layer 1 writes buf)
    int* eidx    = (int*)buf;                         // 1M
    int* aidxs   = eidx + E_TOTAL;                    // 1M
    int* counts  = aidxs + E_TOTAL;                   // NATOMS
    int* row_ptr = counts + NATOMS;                   // NATOMS+1
    int* cursor  = row_ptr + NATOMS + 1;              // NATOMS
    int* bsums   = cursor + NATOMS;                   // NBLK

    hipMemsetAsync(counts, 0, NATOMS * sizeof(int), stream);

    hist_kernel<<<(E_TOTAL + 255) / 256, 256, 0, stream>>>(idnb, counts);
    scan1_kernel<<<NBLK, 256, 0, stream>>>(counts, row_ptr, bsums);
    scan2_kernel<<<1, 256, 0, stream>>>(bsums);
    scan3_kernel<<<NBLK, 256, 0, stream>>>(bsums, row_ptr, cursor);
    scatter_kernel<<<(E_TOTAL + 255) / 256, 256, 0, stream>>>(idnb, cursor, eidx, aidxs);

    edge_kernel<<<NATOMS / APB, 256, 0, stream>>>(x, rbf, eidx, aidxs, row_ptr,
                                                  Wx, bx, Wr, brf,
                                                  c_a, c_b, c_x, acc);

    const int ltiles = (NATOMS + 127) / 128;          // 391
    layer_kernel<<<ltiles, 256, 0, stream>>>(acc, W1, b1, buf, NATOMS);
    layer_kernel<<<ltiles, 256, 0, stream>>>(buf, W2, b2, acc, NATOMS);
    layer3_final_kernel<<<ltiles, 256, 0, stream>>>(acc, W3, b3, Wf, c_f, out, NATOMS);
}

// Round 12
// 399.421 us; speedup vs baseline: 1.6631x; 1.0549x over previous
//
#include <hip/hip_runtime.h>

#define E_TOTAL 1000000
#define EMB     128
#define NRBF    16
#define NATOMS  50000
#define APB     16                         // atoms per block (50000 = 3125*16)
#define NBLK    ((NATOMS + 255) / 256)     // scan blocks

typedef _Float16 f16x8 __attribute__((ext_vector_type(8)));
typedef _Float16 f16x4 __attribute__((ext_vector_type(4)));
typedef float    f32x4 __attribute__((ext_vector_type(4)));

__device__ __forceinline__ float silu_f(float v) {
    return v * (1.0f / (1.0f + __expf(-v)));
}

// LDS row e holds sorted edge sigma(e): lane-quarter lq's C-rows across the
// 4 mt steps then cover sorted positions lq*16..lq*16+15 consecutively.
__device__ __forceinline__ int sigma64(int e) {
    return (((e & 15) >> 2) << 4) + ((e >> 4) << 2) + (e & 3);
}

// ---------------------------------------------------------------------------
// CSR build: counting sort of edge ids by destination atom.
// ---------------------------------------------------------------------------
__global__ __launch_bounds__(256)
void hist_kernel(const int* __restrict__ idnb, int* __restrict__ counts) {
    const int e = blockIdx.x * 256 + threadIdx.x;
    if (e < E_TOTAL) atomicAdd(&counts[idnb[e]], 1);
}

__global__ __launch_bounds__(256)
void scan1_kernel(const int* __restrict__ counts, int* __restrict__ row_ptr,
                  int* __restrict__ bsums) {
    __shared__ int sd[256];
    const int tid = threadIdx.x;
    const int idx = blockIdx.x * 256 + tid;
    const int v = (idx < NATOMS) ? counts[idx] : 0;
    sd[tid] = v;
    __syncthreads();
#pragma unroll
    for (int off = 1; off < 256; off <<= 1) {
        const int t = (tid >= off) ? sd[tid - off] : 0;
        __syncthreads();
        sd[tid] += t;
        __syncthreads();
    }
    if (idx < NATOMS) row_ptr[idx] = sd[tid] - v;
    if (tid == 255) bsums[blockIdx.x] = sd[255];
}

__global__ __launch_bounds__(256)
void scan2_kernel(int* __restrict__ bsums) {
    __shared__ int sd[256];
    const int tid = threadIdx.x;
    const int v = (tid < NBLK) ? bsums[tid] : 0;
    sd[tid] = v;
    __syncthreads();
#pragma unroll
    for (int off = 1; off < 256; off <<= 1) {
        const int t = (tid >= off) ? sd[tid - off] : 0;
        __syncthreads();
        sd[tid] += t;
        __syncthreads();
    }
    if (tid < NBLK) bsums[tid] = sd[tid] - v;
}

__global__ __launch_bounds__(256)
void scan3_kernel(const int* __restrict__ bsums, int* __restrict__ row_ptr,
                  int* __restrict__ cursor) {
    const int idx = blockIdx.x * 256 + threadIdx.x;
    if (idx < NATOMS) {
        const int r = row_ptr[idx] + bsums[blockIdx.x];
        row_ptr[idx] = r;
        cursor[idx]  = r;
    }
    if (idx == 0) row_ptr[NATOMS] = E_TOTAL;
}

__global__ __launch_bounds__(256)
void scatter_kernel(const int* __restrict__ idnb, int* __restrict__ cursor,
                    int* __restrict__ eidx) {
    const int e = blockIdx.x * 256 + threadIdx.x;
    if (e < E_TOTAL) {
        const int a = idnb[e];
        const int p = atomicAdd(&cursor[a], 1);
        eidx[p] = e;
    }
}

// ---------------------------------------------------------------------------
// MFMA edge kernel. Single-buffer LDS (30 KB -> up to 5 blocks/CU), r6-proven
// 2-barrier tile loop, sigma-permuted edge->C-row mapping + carried run-merge
// (r11-proven), fused gate. Relative atom of each sorted position derived
// from the block's 16 scalar row_ptr boundaries (no aidxs array).
// ---------------------------------------------------------------------------
__global__ __launch_bounds__(256, 2)
void edge_kernel(const float* __restrict__ x,
                 const float* __restrict__ rbf,
                 const int*   __restrict__ eidx,
                 const int*   __restrict__ row_ptr,
                 const float* __restrict__ Wx,
                 const float* __restrict__ bx,
                 const float* __restrict__ Wr,
                 const float* __restrict__ br,
                 const float* __restrict__ c_a,
                 const float* __restrict__ c_b,
                 const float* __restrict__ c_x,
                 float* __restrict__ acc)
{
    __shared__ _Float16 sX[64 * 128];   // 16 KB, XOR-swizzled 8-f16 groups
    __shared__ _Float16 sR[64 * 40];    // 5 KB, stride-40 pad, k>=16 zero
    __shared__ float    sAcc[APB][132]; // 8.4 KB
    __shared__ int      sAid[64];       // rel-atom of sorted pos (tile-local)

    const int tid  = threadIdx.x;
    const int w    = tid >> 6;
    const int lane = tid & 63;
    const int lq   = lane >> 4;
    const int lm   = lane & 15;

    const int aBase = blockIdx.x * APB;

    // scalar row_ptr boundary table (uniform -> SGPRs)
    int rp[APB];
#pragma unroll
    for (int a = 0; a < APB; ++a) rp[a] = row_ptr[aBase + a];
    const int eBeg = rp[0];
    const int eEnd = row_ptr[aBase + APB];
    const int nEdge = eEnd - eBeg;
    const int ntile = (nEdge + 63) >> 6;

    const float ca = c_a[0];
    const float sc = c_b[0] * c_x[0];
    const int col0 = w * 32 + lm;
    const int col1 = col0 + 16;
    const float bx0 = bx[col0], bx1 = bx[col1];
    const float br0 = br[col0], br1 = br[col1];

    // ---- hoist split-W fragments from global, once per block ----
    f16x8 wxh[4][2], wxl[4][2], wrh[2], wrl[2];
#pragma unroll
    for (int ks = 0; ks < 4; ++ks)
#pragma unroll
        for (int nt = 0; nt < 2; ++nt) {
            const int n = w * 32 + nt * 16 + lm;
            f16x8 h8, l8;
#pragma unroll
            for (int j = 0; j < 8; ++j) {
                const int k = ks * 32 + lq * 8 + j;
                const float v = Wx[k * EMB + n];
                const _Float16 hv = (_Float16)v;
                h8[j] = hv;
                l8[j] = (_Float16)(v - (float)hv);
            }
            wxh[ks][nt] = h8;
            wxl[ks][nt] = l8;
        }
#pragma unroll
    for (int nt = 0; nt < 2; ++nt) {
        const int n = w * 32 + nt * 16 + lm;
        f16x8 h8, l8;
#pragma unroll
        for (int j = 0; j < 8; ++j) {
            const int k = lq * 8 + j;
            const float v = (k < NRBF) ? Wr[k * EMB + n] : 0.f;
            const _Float16 hv = (_Float16)v;
            h8[j] = hv;
            l8[j] = (_Float16)(v - (float)hv);
        }
        wrh[nt] = h8;
        wrl[nt] = l8;
    }

    // init LDS: zero accumulator; zero sR k in [16,40)
    for (int f = tid; f < APB * 132; f += 256) ((float*)sAcc)[f] = 0.f;
    for (int f = tid; f < 64 * 24; f += 256)
        sR[(f / 24) * 40 + 16 + (f % 24)] = (_Float16)0.f;

    float4 px[8];
    float4 pr;
    int    prel = -1;

    auto prefetch = [&](int t) {
        const int nb = eBeg + t * 64;
#pragma unroll
        for (int i = 0; i < 8; ++i) {
            const int e = (tid >> 5) + i * 8;            // LDS row
            const int eid = eidx[min(nb + sigma64(e), eEnd - 1)];
            px[i] = *(const float4*)(x + (size_t)eid * EMB + (tid & 31) * 4);
        }
        {
            const int er = tid >> 2;                     // LDS row (rbf)
            const int eid = eidx[min(nb + sigma64(er), eEnd - 1)];
            pr = *(const float4*)(rbf + (size_t)eid * NRBF + (tid & 3) * 4);
        }
        // rel-atom of sorted position nb+tid from scalar boundaries
        if (tid < 64) {
            const int pos = nb + tid;
            if (pos >= eEnd) {
                prel = -1;
            } else {
                int rel = 0;
#pragma unroll
                for (int a = 1; a < APB; ++a) rel += (pos >= rp[a]) ? 1 : 0;
                prel = rel;
            }
        }
    };

    auto write_lds = [&]() {
#pragma unroll
        for (int i = 0; i < 8; ++i) {
            const int e = (tid >> 5) + i * 8;
            const int kb = (tid & 31) * 4;
            const int idx = (e * 128 + kb) ^ ((e & 7) << 3);
            f16x4 h4 = {(_Float16)px[i].x, (_Float16)px[i].y,
                        (_Float16)px[i].z, (_Float16)px[i].w};
            *(f16x4*)&sX[idx] = h4;
        }
        {
            const int er = tid >> 2;
            const int kb = (tid & 3) * 4;
            f16x4 r4 = {(_Float16)(pr.x * ca), (_Float16)(pr.y * ca),
                        (_Float16)(pr.z * ca), (_Float16)(pr.w * ca)};
            *(f16x4*)&sR[er * 40 + kb] = r4;
        }
        if (tid < 64) sAid[tid] = prel;
    };

    if (ntile > 0) prefetch(0);

    for (int t = 0; t < ntile; ++t) {
        __syncthreads();                 // prev tile's readers (or init) done
        write_lds();
        __syncthreads();                 // tile t visible
        if (t + 1 < ntile) prefetch(t + 1);   // in flight during compute

        // run-merge state carried across the whole tile (16-edge span/lane)
        int   curA = -2;
        float a0v = 0.f, a1v = 0.f;

        // epilogue for one mt's accumulators (fused gate + carried merge)
        auto epi = [&](const f32x4 hac[2], const f32x4 gac[2], int mt) {
            const int pbase = lq * 16 + mt * 4;
            float v0[4], v1[4];
#pragma unroll
            for (int r = 0; r < 4; ++r) {
                const float g0 = gac[0][r] + br0, h0 = hac[0][r] + bx0;
                const float g1 = gac[1][r] + br1, h1 = hac[1][r] + bx1;
                const float d0 = (1.f + __expf(-g0)) * (1.f + __expf(-h0));
                const float d1 = (1.f + __expf(-g1)) * (1.f + __expf(-h1));
                v0[r] = sc * g0 * h0 * __builtin_amdgcn_rcpf(d0);
                v1[r] = sc * g1 * h1 * __builtin_amdgcn_rcpf(d1);
            }
#pragma unroll
            for (int r = 0; r < 4; ++r) {
                const int rel = sAid[pbase + r];
                if (rel != curA) {                  // rarely taken (run ~20)
                    if (curA >= 0) {
                        atomicAdd(&sAcc[curA][col0], a0v);
                        atomicAdd(&sAcc[curA][col1], a1v);
                    }
                    curA = rel; a0v = 0.f; a1v = 0.f;
                }
                a0v += v0[r];
                a1v += v1[r];
            }
        };

        // MFMA for one mt into the given accumulators
        auto mfma_mt = [&](f32x4 hac[2], f32x4 gac[2], int mt) {
#pragma unroll
            for (int nt = 0; nt < 2; ++nt) { hac[nt] = 0.f; gac[nt] = 0.f; }
            const int m = mt * 16 + lm;
            const f16x8 rh = *(const f16x8*)&sR[m * 40 + lq * 8];
#pragma unroll
            for (int nt = 0; nt < 2; ++nt) {
                gac[nt] = __builtin_amdgcn_mfma_f32_16x16x32_f16(rh, wrh[nt], gac[nt], 0, 0, 0);
                gac[nt] = __builtin_amdgcn_mfma_f32_16x16x32_f16(rh, wrl[nt], gac[nt], 0, 0, 0);
            }
#pragma unroll
            for (int ks = 0; ks < 4; ++ks) {
                const int xi = (m * 128 + ks * 32 + lq * 8) ^ ((m & 7) << 3);
                const f16x8 xh = *(const f16x8*)&sX[xi];
#pragma unroll
                for (int nt = 0; nt < 2; ++nt) {
                    hac[nt] = __builtin_amdgcn_mfma_f32_16x16x32_f16(xh, wxh[ks][nt], hac[nt], 0, 0, 0);
                    hac[nt] = __builtin_amdgcn_mfma_f32_16x16x32_f16(xh, wxl[ks][nt], hac[nt], 0, 0, 0);
                }
            }
        };

        // 2-mt groups: two independent MFMA chains in flight per epilogue pair
#pragma unroll
        for (int g = 0; g < 2; ++g) {
            f32x4 hacA[2], gacA[2], hacB[2], gacB[2];
            mfma_mt(hacA, gacA, g * 2);
            mfma_mt(hacB, gacB, g * 2 + 1);
            epi(hacA, gacA, g * 2);
            epi(hacB, gacB, g * 2 + 1);
        }

        if (curA >= 0) {                            // final flush per tile
            atomicAdd(&sAcc[curA][col0], a0v);
            atomicAdd(&sAcc[curA][col1], a1v);
        }
    }

    __syncthreads();   // sAcc atomics (or zero-init) visible
    {
        const int r = tid >> 4;
        const int c = (tid & 15) * 8;
        float* dst = acc + (size_t)(aBase + r) * EMB + c;
        *(float4*)(dst)     = *(const float4*)&sAcc[r][c];
        *(float4*)(dst + 4) = *(const float4*)&sAcc[r][c + 4];
    }
}

// ---------------------------------------------------------------------------
// MFMA atom-MLP layer: Y = silu(X @ W + b). 2 subtiles of 64 rows per block.
// ---------------------------------------------------------------------------
__global__ __launch_bounds__(256, 2)
void layer_kernel(const float* __restrict__ X,
                  const float* __restrict__ W,
                  const float* __restrict__ b,
                  float* __restrict__ Y, int M)
{
    __shared__ _Float16 sX[64 * 128];

    const int tid  = threadIdx.x;
    const int w    = tid >> 6;
    const int lane = tid & 63;
    const int lq   = lane >> 4;
    const int lm   = lane & 15;

    const int col0 = w * 32 + lm;
    const int col1 = col0 + 16;
    const float b0 = b[col0], b1 = b[col1];

    f16x8 wh[4][2], wl[4][2];
#pragma unroll
    for (int ks = 0; ks < 4; ++ks)
#pragma unroll
        for (int nt = 0; nt < 2; ++nt) {
            const int n = w * 32 + nt * 16 + lm;
            f16x8 h8, l8;
#pragma unroll
            for (int j = 0; j < 8; ++j) {
                const int k = ks * 32 + lq * 8 + j;
                const float v = W[k * EMB + n];
                const _Float16 hv = (_Float16)v;
                h8[j] = hv;
                l8[j] = (_Float16)(v - (float)hv);
            }
            wh[ks][nt] = h8;
            wl[ks][nt] = l8;
        }

#pragma unroll
    for (int sub = 0; sub < 2; ++sub) {
        const int base = blockIdx.x * 128 + sub * 64;
        __syncthreads();
#pragma unroll
        for (int i = 0; i < 8; ++i) {
            const int e = (tid >> 5) + i * 8;
            const int row = min(base + e, M - 1);
            const float4 v = *(const float4*)(X + (size_t)row * EMB + (tid & 31) * 4);
            const int kb = (tid & 31) * 4;
            const int idx = (e * 128 + kb) ^ ((e & 7) << 3);
            f16x4 h4 = {(_Float16)v.x, (_Float16)v.y, (_Float16)v.z, (_Float16)v.w};
            *(f16x4*)&sX[idx] = h4;
        }
        __syncthreads();

#pragma unroll
        for (int mth = 0; mth < 2; ++mth) {
            f32x4 hac[2][2];
#pragma unroll
            for (int mi = 0; mi < 2; ++mi)
#pragma unroll
                for (int nt = 0; nt < 2; ++nt) hac[mi][nt] = 0.f;

#pragma unroll
            for (int mi = 0; mi < 2; ++mi) {
                const int m = (mth * 2 + mi) * 16 + lm;
#pragma unroll
                for (int ks = 0; ks < 4; ++ks) {
                    const int xi = (m * 128 + ks * 32 + lq * 8) ^ ((m & 7) << 3);
                    const f16x8 xh = *(const f16x8*)&sX[xi];
#pragma unroll
                    for (int nt = 0; nt < 2; ++nt) {
                        hac[mi][nt] = __builtin_amdgcn_mfma_f32_16x16x32_f16(xh, wh[ks][nt], hac[mi][nt], 0, 0, 0);
                        hac[mi][nt] = __builtin_amdgcn_mfma_f32_16x16x32_f16(xh, wl[ks][nt], hac[mi][nt], 0, 0, 0);
                    }
                }
            }
#pragma unroll
            for (int mi = 0; mi < 2; ++mi) {
                const int rb = base + (mth * 2 + mi) * 16 + lq * 4;
#pragma unroll
                for (int r = 0; r < 4; ++r) {
                    const int row = rb + r;
                    if (row < M) {
                        Y[(size_t)row * EMB + col0] = silu_f(hac[mi][0][r] + b0);
                        Y[(size_t)row * EMB + col1] = silu_f(hac[mi][1][r] + b1);
                    }
                }
            }
        }
    }
}

// ---------------------------------------------------------------------------
// Fused layer-3 + final projection: out[row] = (silu(X@W3+b3) @ Wf) * cf.
// ---------------------------------------------------------------------------
__global__ __launch_bounds__(256, 2)
void layer3_final_kernel(const float* __restrict__ X,
                         const float* __restrict__ W,
                         const float* __restrict__ b,
                         const float* __restrict__ Wf,
                         const float* __restrict__ cf,
                         float* __restrict__ out, int M)
{
    __shared__ _Float16 sX[64 * 128];
    __shared__ float    sOut[128];

    const int tid  = threadIdx.x;
    const int w    = tid >> 6;
    const int lane = tid & 63;
    const int lq   = lane >> 4;
    const int lm   = lane & 15;

    const int col0 = w * 32 + lm;
    const int col1 = col0 + 16;
    const float b0 = b[col0], b1 = b[col1];
    const float wf0 = Wf[col0], wf1 = Wf[col1];
    const float cfv = cf[0];

    if (tid < 128) sOut[tid] = 0.f;

    f16x8 wh[4][2], wl[4][2];
#pragma unroll
    for (int ks = 0; ks < 4; ++ks)
#pragma unroll
        for (int nt = 0; nt < 2; ++nt) {
            const int n = w * 32 + nt * 16 + lm;
            f16x8 h8, l8;
#pragma unroll
            for (int j = 0; j < 8; ++j) {
                const int k = ks * 32 + lq * 8 + j;
                const float v = W[k * EMB + n];
                const _Float16 hv = (_Float16)v;
                h8[j] = hv;
                l8[j] = (_Float16)(v - (float)hv);
            }
            wh[ks][nt] = h8;
            wl[ks][nt] = l8;
        }

#pragma unroll
    for (int sub = 0; sub < 2; ++sub) {
        const int base = blockIdx.x * 128 + sub * 64;
        __syncthreads();
#pragma unroll
        for (int i = 0; i < 8; ++i) {
            const int e = (tid >> 5) + i * 8;
            const int row = min(base + e, M - 1);
            const float4 v = *(const float4*)(X + (size_t)row * EMB + (tid & 31) * 4);
            const int kb = (tid & 31) * 4;
            const int idx = (e * 128 + kb) ^ ((e & 7) << 3);
            f16x4 h4 = {(_Float16)v.x, (_Float16)v.y, (_Float16)v.z, (_Float16)v.w};
            *(f16x4*)&sX[idx] = h4;
        }
        __syncthreads();

#pragma unroll
        for (int mth = 0; mth < 2; ++mth) {
            f32x4 hac[2][2];
#pragma unroll
            for (int mi = 0; mi < 2; ++mi)
#pragma unroll
                for (int nt = 0; nt < 2; ++nt) hac[mi][nt] = 0.f;

#pragma unroll
            for (int mi = 0; mi < 2; ++mi) {
                const int m = (mth * 2 + mi) * 16 + lm;
#pragma unroll
                for (int ks = 0; ks < 4; ++ks) {
                    const int xi = (m * 128 + ks * 32 + lq * 8) ^ ((m & 7) << 3);
                    const f16x8 xh = *(const f16x8*)&sX[xi];
#pragma unroll
                    for (int nt = 0; nt < 2; ++nt) {
                        hac[mi][nt] = __builtin_amdgcn_mfma_f32_16x16x32_f16(xh, wh[ks][nt], hac[mi][nt], 0, 0, 0);
                        hac[mi][nt] = __builtin_amdgcn_mfma_f32_16x16x32_f16(xh, wl[ks][nt], hac[mi][nt], 0, 0, 0);
                    }
                }
            }
#pragma unroll
            for (int mi = 0; mi < 2; ++mi) {
                const int lrow = sub * 64 + (mth * 2 + mi) * 16 + lq * 4;
#pragma unroll
                for (int r = 0; r < 4; ++r) {
                    const float o0 = silu_f(hac[mi][0][r] + b0);
                    const float o1 = silu_f(hac[mi][1][r] + b1);
                    float p = o0 * wf0 + o1 * wf1;
#pragma unroll
                    for (int off = 1; off < 16; off <<= 1)
                        p += __shfl_xor(p, off);
                    if (lm == 0 && base + (mth * 2 + mi) * 16 + lq * 4 + r < M)
                        atomicAdd(&sOut[lrow + r], p);
                }
            }
        }
    }

    __syncthreads();
    if (tid < 128) {
        const int row = blockIdx.x * 128 + tid;
        if (row < M) out[row] = sOut[tid] * cfv;
    }
}

extern "C" void kernel_launch(void* const* d_in, const int* in_sizes, int n_in,
                              void* d_out, int out_size, void* d_ws, size_t ws_size,
                              hipStream_t stream) {
    const float* x    = (const float*)d_in[0];
    const float* rbf  = (const float*)d_in[1];
    const int*   idnb = (const int*)  d_in[2];
    // d_in[3] = n_atoms (fixed 50000)
    const float* Wx   = (const float*)d_in[4];
    const float* bx   = (const float*)d_in[5];
    const float* Wr   = (const float*)d_in[6];
    const float* brf  = (const float*)d_in[7];
    const float* W1   = (const float*)d_in[8];
    const float* b1   = (const float*)d_in[9];
    const float* W2   = (const float*)d_in[10];
    const float* b2   = (const float*)d_in[11];
    const float* W3   = (const float*)d_in[12];
    const float* b3   = (const float*)d_in[13];
    const float* Wf   = (const float*)d_in[14];
    const float* c_a  = (const float*)d_in[15];
    const float* c_b  = (const float*)d_in[16];
    const float* c_x  = (const float*)d_in[17];
    const float* c_f  = (const float*)d_in[18];

    float* out = (float*)d_out;
    float* acc = (float*)d_ws;                        // [NATOMS][128] f32
    float* buf = acc + (size_t)NATOMS * EMB;          // [NATOMS][128] f32
    // CSR scratch inside buf (dead before layer 1 writes buf)
    int* eidx    = (int*)buf;                         // 1M
    int* counts  = eidx + E_TOTAL;                    // NATOMS
    int* row_ptr = counts + NATOMS;                   // NATOMS+1
    int* cursor  = row_ptr + NATOMS + 1;              // NATOMS
    int* bsums   = cursor + NATOMS;                   // NBLK

    hipMemsetAsync(counts, 0, NATOMS * sizeof(int), stream);

    hist_kernel<<<(E_TOTAL + 255) / 256, 256, 0, stream>>>(idnb, counts);
    scan1_kernel<<<NBLK, 256, 0, stream>>>(counts, row_ptr, bsums);
    scan2_kernel<<<1, 256, 0, stream>>>(bsums);
    scan3_kernel<<<NBLK, 256, 0, stream>>>(bsums, row_ptr, cursor);
    scatter_kernel<<<(E_TOTAL + 255) / 256, 256, 0, stream>>>(idnb, cursor, eidx);

    edge_kernel<<<NATOMS / APB, 256, 0, stream>>>(x, rbf, eidx, row_ptr,
                                                  Wx, bx, Wr, brf,
                                                  c_a, c_b, c_x, acc);

    const int ltiles = (NATOMS + 127) / 128;          // 391
    layer_kernel<<<ltiles, 256, 0, stream>>>(acc, W1, b1, buf, NATOMS);
    layer_kernel<<<ltiles, 256, 0, stream>>>(buf, W2, b2, acc, NATOMS);
    layer3_final_kernel<<<ltiles, 256, 0, stream>>>(acc, W3, b3, Wf, c_f, out, NATOMS);
}